// Round 3
// baseline (471.357 us; speedup 1.0000x reference)
//
#include <hip/hip_runtime.h>
#include <stdint.h>

#define NLAYERS 3
#define NQ 8
#define DIM 256          // 2^NQ
#define HALF 128         // measured output amplitudes
#define BATCH 131072

typedef float  f32x4  __attribute__((ext_vector_type(4)));
typedef __bf16 bf16x8 __attribute__((ext_vector_type(8)));

__device__ __forceinline__ unsigned short f2bf(float f){
    union { float f; uint32_t u; } v; v.f = f;
    uint32_t u = v.u;
    u += 0x7fffu + ((u >> 16) & 1u);   // round-to-nearest-even
    return (unsigned short)(u >> 16);
}

__device__ __forceinline__ float2 cmul(float2 a, float2 b){
    return make_float2(a.x*b.x - a.y*b.y, a.x*b.y + a.y*b.x);
}

// async 16B global -> LDS (lane dest = uniform base + lane*16)
__device__ __forceinline__ void gload_lds16(void* lds, const void* g){
    __builtin_amdgcn_global_load_lds(
        (const __attribute__((address_space(1))) unsigned int*)g,
        (__attribute__((address_space(3))) unsigned int*)lds,
        16, 0, 0);
}

// ---------------------------------------------------------------------------
// Kernel 1: simulate circuit on basis state e_j (block j) and emit the
// 128x256 complex matrix W as two bf16 planes (Wre, Wim), stored PRE-SWIZZLED
// (granule g of row n lands at slot g ^ (n&7)) so kernel 2 can DMA the image
// linearly into LDS and read conflict-free with ds_read_b128.
// Image: ushort[65536] = 128 KB. [0,32768): Wre, [32768,65536): Wim.
// ---------------------------------------------------------------------------
__global__ __launch_bounds__(256) void build_w_kernel(const float* __restrict__ params,
                                                      unsigned short* __restrict__ W){
    __shared__ float2 st[2][DIM];
    __shared__ float2 gm[NLAYERS*NQ][4];   // U0a,U0b,U1a,U1b per gate
    const int j = blockIdx.x;
    const int i = threadIdx.x;

    if (i < NLAYERS*NQ){
        const float* pp = params + i*3;
        float hx = 0.5f*pp[0], hy = 0.5f*pp[1], hz = 0.5f*pp[2];
        float cx = cosf(hx), sx = sinf(hx);
        float cy = cosf(hy), sy = sinf(hy);
        float cz = cosf(hz), sz = sinf(hz);
        float2 ezm = make_float2(cz, -sz), ezp = make_float2(cz, sz);
        float2 m00 = make_float2( cy*cx,  sy*sx);
        float2 m01 = make_float2(-sy*cx, -cy*sx);
        float2 m10 = make_float2( sy*cx, -cy*sx);
        float2 m11 = make_float2( cy*cx, -sy*sx);
        gm[i][0] = cmul(ezm, m00);
        gm[i][1] = cmul(ezm, m01);
        gm[i][2] = cmul(ezp, m10);
        gm[i][3] = cmul(ezp, m11);
    }

    // composed CNOT-ring permutation (params-independent, same all layers)
    int psrc = i;
    #pragma unroll
    for (int q = NQ-1; q >= 0; --q){
        int c  = 7 - q;
        int tb = 7 - ((q + 1) & 7);
        psrc = ((psrc >> c) & 1) ? (psrc ^ (1 << tb)) : psrc;
    }

    int cur = 0;
    st[0][i] = make_float2(i == j ? 1.0f : 0.0f, 0.0f);
    __syncthreads();

    for (int l = 0; l < NLAYERS; ++l){
        for (int q = 0; q < NQ; ++q){
            float2 U0a = gm[l*NQ+q][0], U0b = gm[l*NQ+q][1];
            float2 U1a = gm[l*NQ+q][2], U1b = gm[l*NQ+q][3];
            int p  = 7 - q;
            int bs = (i >> p) & 1;
            int i0 = i & ~(1 << p), i1 = i | (1 << p);
            float2 a0 = st[cur][i0], a1 = st[cur][i1];
            float2 ua = bs ? U1a : U0a;
            float2 ub = bs ? U1b : U0b;
            float2 r;
            r.x = ua.x*a0.x - ua.y*a0.y + ub.x*a1.x - ub.y*a1.y;
            r.y = ua.x*a0.y + ua.y*a0.x + ub.x*a1.y + ub.y*a1.x;
            st[cur ^ 1][i] = r;
            cur ^= 1;
            __syncthreads();
        }
        // fused CNOT ring
        float2 r = st[cur][psrc];
        st[cur ^ 1][i] = r;
        cur ^= 1;
        __syncthreads();
    }

    // column j of W: thread i<128 -> Wre[i][j], thread i>=128 -> Wim[i-128][j]
    const int m = i & 127;
    float2 a = st[cur][m];
    // swizzled offset (ushort units): row m (512 B = 32 granules of 16 B)
    const uint32_t off = (uint32_t)m*256u
                       + ((((uint32_t)j >> 3) ^ ((uint32_t)m & 7u)) << 3)
                       + ((uint32_t)j & 7u);
    if (i < 128) W[off]          = f2bf(a.x);
    else         W[32768u + off] = f2bf(a.y);
}

// ---------------------------------------------------------------------------
// Kernel 2: out[m] = sum_j |sum_k W[j][k]*(sr[m][k] + i si[m][k])|^2
// 256 blocks x 512 threads (8 waves/CU = 2 waves/SIMD -> 256 VGPR/wave
// budget; the round-2 1024-thread version capped at 128 and spilled).
// B resident in 128 KB LDS (one barrier total). Each wave owns 64 rows =
// 4 tiles of 16. DEPTH-8 register pipeline in NAMED slot variables
// (macro-expanded; zero runtime-indexed arrays): tile t's step S consumes
// slot S and refills it with tile t+1's kstep S, so the pipeline never
// drains. 8 waves x 512 B = 4 KB/CU in flight.
// ---------------------------------------------------------------------------

#define LOADSLOT(S, PR, PI)                          \
    sR0_##S = *(const float4*)((PR) + (S)*32);       \
    sR1_##S = *(const float4*)((PR) + (S)*32 + 4);   \
    sQ0_##S = *(const float4*)((PI) + (S)*32);       \
    sQ1_##S = *(const float4*)((PI) + (S)*32 + 4);

#define STEP(S)                                                                 \
{                                                                               \
    union { float4 v; uint32_t u[4]; } ha_, hb_;                                \
    union { uint32_t u[4]; bf16x8 f; } pr_, pi_, pn_;                           \
    ha_.v = sR0_##S; hb_.v = sR1_##S;                                           \
    pr_.u[0] = __builtin_amdgcn_perm(ha_.u[1], ha_.u[0], 0x07060302);           \
    pr_.u[1] = __builtin_amdgcn_perm(ha_.u[3], ha_.u[2], 0x07060302);           \
    pr_.u[2] = __builtin_amdgcn_perm(hb_.u[1], hb_.u[0], 0x07060302);           \
    pr_.u[3] = __builtin_amdgcn_perm(hb_.u[3], hb_.u[2], 0x07060302);           \
    ha_.v = sQ0_##S; hb_.v = sQ1_##S;                                           \
    pi_.u[0] = __builtin_amdgcn_perm(ha_.u[1], ha_.u[0], 0x07060302);           \
    pi_.u[1] = __builtin_amdgcn_perm(ha_.u[3], ha_.u[2], 0x07060302);           \
    pi_.u[2] = __builtin_amdgcn_perm(hb_.u[1], hb_.u[0], 0x07060302);           \
    pi_.u[3] = __builtin_amdgcn_perm(hb_.u[3], hb_.u[2], 0x07060302);           \
    pn_.u[0] = pi_.u[0] ^ 0x80008000u;                                          \
    pn_.u[1] = pi_.u[1] ^ 0x80008000u;                                          \
    pn_.u[2] = pi_.u[2] ^ 0x80008000u;                                          \
    pn_.u[3] = pi_.u[3] ^ 0x80008000u;                                          \
    const bf16x8 fr_ = pr_.f;   /* bf16(sr) */                                  \
    const bf16x8 fi_ = pi_.f;   /* bf16(si) */                                  \
    const bf16x8 fn_ = pn_.f;   /* -bf16(si) */                                 \
    /* refill slot S with next tile's kstep S (clamped: last tile re-reads) */  \
    LOADSLOT(S, narq, naiq)                                                     \
    const int ub_ = l15*256 + ((((S<<2) + quad) ^ xq) << 3);                    \
    const unsigned short* bre_ = &Bs[ub_];                                      \
    const unsigned short* bim_ = &Bs[32768 + ub_];                              \
    __builtin_amdgcn_s_setprio(1);                                              \
    _Pragma("unroll")                                                           \
    for (int jf = 0; jf < 8; ++jf){                                             \
        const bf16x8 br = *(const bf16x8*)(bre_ + jf*4096);                     \
        const bf16x8 bi = *(const bf16x8*)(bim_ + jf*4096);                     \
        accR[jf] = __builtin_amdgcn_mfma_f32_16x16x32_bf16(fr_, br, accR[jf], 0, 0, 0); \
        accR[jf] = __builtin_amdgcn_mfma_f32_16x16x32_bf16(fn_, bi, accR[jf], 0, 0, 0); \
        accI[jf] = __builtin_amdgcn_mfma_f32_16x16x32_bf16(fr_, bi, accI[jf], 0, 0, 0); \
        accI[jf] = __builtin_amdgcn_mfma_f32_16x16x32_bf16(fi_, br, accI[jf], 0, 0, 0); \
    }                                                                           \
    __builtin_amdgcn_s_setprio(0);                                              \
}

__global__ __launch_bounds__(512, 2) void qform2_kernel(const float* __restrict__ sr,
                                                        const float* __restrict__ si,
                                                        const unsigned short* __restrict__ W,
                                                        float* __restrict__ out){
    __shared__ unsigned short Bs[65536];   // 128 KB: [0,32768) Wre, [32768,65536) Wim

    const int tid  = threadIdx.x;
    const int lane = tid & 63;
    const int w    = tid >> 6;        // 0..7
    const int l15  = lane & 15;
    const int quad = lane >> 4;       // 0..3
    const int xq   = l15 & 7;

    const size_t rowbase = (size_t)blockIdx.x * 512 + (size_t)w * 64;

    // per-lane A pointers (include the quad k-offset once)
    const float* arq = sr + (rowbase + l15) * DIM + quad*8;
    const float* aiq = si + (rowbase + l15) * DIM + quad*8;

    // depth-8 pipeline: named slots (no arrays -> no scratch)
    float4 sR0_0, sR1_0, sQ0_0, sQ1_0;
    float4 sR0_1, sR1_1, sQ0_1, sQ1_1;
    float4 sR0_2, sR1_2, sQ0_2, sQ1_2;
    float4 sR0_3, sR1_3, sQ0_3, sQ1_3;
    float4 sR0_4, sR1_4, sQ0_4, sQ1_4;
    float4 sR0_5, sR1_5, sQ0_5, sQ1_5;
    float4 sR0_6, sR1_6, sQ0_6, sQ1_6;
    float4 sR0_7, sR1_7, sQ0_7, sQ1_7;

    // prologue: issue tile 0's full k (8 ksteps x 64 B) BEFORE B staging so
    // the A stream overlaps the DMA + barrier.
    LOADSLOT(0, arq, aiq)
    LOADSLOT(1, arq, aiq)
    LOADSLOT(2, arq, aiq)
    LOADSLOT(3, arq, aiq)
    LOADSLOT(4, arq, aiq)
    LOADSLOT(5, arq, aiq)
    LOADSLOT(6, arq, aiq)
    LOADSLOT(7, arq, aiq)

    // ---- stage W image linearly: 128 chunks x 1 KB (image is pre-swizzled)
    #pragma unroll
    for (int r = 0; r < 16; ++r){
        const int c = w*16 + r;                      // 0..127
        gload_lds16(&Bs[c*512], W + (size_t)c*512 + lane*8);
    }
    __syncthreads();    // drains vmcnt -> DMA complete (A prologue also back)

    f32x4 accR[8], accI[8];
    const f32x4 z = {0.0f, 0.0f, 0.0f, 0.0f};
    #pragma unroll
    for (int jf = 0; jf < 8; ++jf){ accR[jf] = z; accI[jf] = z; }

    #pragma unroll 1
    for (int t = 0; t < 4; ++t){
        // next-tile pointers (clamped on last tile: harmless L1-hit re-reads)
        const float* narq = (t < 3) ? (arq + 16*DIM) : arq;
        const float* naiq = (t < 3) ? (aiq + 16*DIM) : aiq;

        STEP(0)
        STEP(1)
        STEP(2)
        STEP(3)
        STEP(4)
        STEP(5)
        STEP(6)
        STEP(7)

        // ---- tile epilogue: out[row] = sum_j Re^2 + Im^2
        // C/D layout: row = quad*4 + r, col = jf*16 + l15
        {
            float sacc[4];
            #pragma unroll
            for (int r = 0; r < 4; ++r){
                float tt = 0.0f;
                #pragma unroll
                for (int jf = 0; jf < 8; ++jf){
                    const float vr = accR[jf][r];
                    const float vi = accI[jf][r];
                    tt += vr*vr + vi*vi;
                }
                tt += __shfl_xor(tt, 1);
                tt += __shfl_xor(tt, 2);
                tt += __shfl_xor(tt, 4);
                tt += __shfl_xor(tt, 8);
                sacc[r] = tt;
            }
            if (l15 == 0){
                float4 o; o.x = sacc[0]; o.y = sacc[1]; o.z = sacc[2]; o.w = sacc[3];
                *(float4*)(out + rowbase + t*16 + quad*4) = o;
            }
            if (t < 3){
                #pragma unroll
                for (int jf = 0; jf < 8; ++jf){ accR[jf] = z; accI[jf] = z; }
            }
        }

        arq = narq;
        aiq = naiq;
    }
}

extern "C" void kernel_launch(void* const* d_in, const int* in_sizes, int n_in,
                              void* d_out, int out_size, void* d_ws, size_t ws_size,
                              hipStream_t stream){
    const float* params = (const float*)d_in[0];
    const float* sr     = (const float*)d_in[1];
    const float* si     = (const float*)d_in[2];
    unsigned short* Wimg = (unsigned short*)d_ws;   // 128 KB image
    float* out          = (float*)d_out;

    build_w_kernel<<<dim3(DIM), dim3(256), 0, stream>>>(params, Wimg);
    qform2_kernel<<<dim3(256), dim3(512), 0, stream>>>(sr, si, Wimg, out);
}

// Round 5
// 294.702 us; speedup vs baseline: 1.5994x; 1.5994x over previous
//
#include <hip/hip_runtime.h>
#include <stdint.h>

#define NLAYERS 3
#define NQ 8
#define DIM 256          // 2^NQ
#define BATCH 131072

typedef float  f32x4  __attribute__((ext_vector_type(4)));
typedef __bf16 bf16x8 __attribute__((ext_vector_type(8)));

__device__ __forceinline__ unsigned short f2bf(float f){
    union { float f; uint32_t u; } v; v.f = f;
    uint32_t u = v.u;
    u += 0x7fffu + ((u >> 16) & 1u);   // round-to-nearest-even
    return (unsigned short)(u >> 16);
}

__device__ __forceinline__ float2 cmul(float2 a, float2 b){
    return make_float2(a.x*b.x - a.y*b.y, a.x*b.y + a.y*b.x);
}

// async 16B global -> LDS (lane dest = uniform base + lane*16)
__device__ __forceinline__ void gload_lds16(void* lds, const void* g){
    __builtin_amdgcn_global_load_lds(
        (const __attribute__((address_space(1))) unsigned int*)g,
        (__attribute__((address_space(3))) unsigned int*)lds,
        16, 0, 0);
}

// ---------------------------------------------------------------------------
// Kernel 1: simulate circuit on basis state e_j (block j) and emit the
// 128x256 complex matrix W as two PLAIN row-major bf16 planes:
//   Wre[m][k] at W[m*256+k], Wim at W[32768 + m*256+k]   (128 KB total)
// ---------------------------------------------------------------------------
__global__ __launch_bounds__(256) void build_w_kernel(const float* __restrict__ params,
                                                      unsigned short* __restrict__ W){
    __shared__ float2 st[2][DIM];
    __shared__ float2 gm[NLAYERS*NQ][4];   // U0a,U0b,U1a,U1b per gate
    const int j = blockIdx.x;
    const int i = threadIdx.x;

    if (i < NLAYERS*NQ){
        const float* pp = params + i*3;
        float hx = 0.5f*pp[0], hy = 0.5f*pp[1], hz = 0.5f*pp[2];
        float cx = cosf(hx), sx = sinf(hx);
        float cy = cosf(hy), sy = sinf(hy);
        float cz = cosf(hz), sz = sinf(hz);
        float2 ezm = make_float2(cz, -sz), ezp = make_float2(cz, sz);
        float2 m00 = make_float2( cy*cx,  sy*sx);
        float2 m01 = make_float2(-sy*cx, -cy*sx);
        float2 m10 = make_float2( sy*cx, -cy*sx);
        float2 m11 = make_float2( cy*cx, -sy*sx);
        gm[i][0] = cmul(ezm, m00);
        gm[i][1] = cmul(ezm, m01);
        gm[i][2] = cmul(ezp, m10);
        gm[i][3] = cmul(ezp, m11);
    }

    // composed CNOT-ring permutation (params-independent, same all layers)
    int psrc = i;
    #pragma unroll
    for (int q = NQ-1; q >= 0; --q){
        int c  = 7 - q;
        int tb = 7 - ((q + 1) & 7);
        psrc = ((psrc >> c) & 1) ? (psrc ^ (1 << tb)) : psrc;
    }

    int cur = 0;
    st[0][i] = make_float2(i == j ? 1.0f : 0.0f, 0.0f);
    __syncthreads();

    for (int l = 0; l < NLAYERS; ++l){
        for (int q = 0; q < NQ; ++q){
            float2 U0a = gm[l*NQ+q][0], U0b = gm[l*NQ+q][1];
            float2 U1a = gm[l*NQ+q][2], U1b = gm[l*NQ+q][3];
            int p  = 7 - q;
            int bs = (i >> p) & 1;
            int i0 = i & ~(1 << p), i1 = i | (1 << p);
            float2 a0 = st[cur][i0], a1 = st[cur][i1];
            float2 ua = bs ? U1a : U0a;
            float2 ub = bs ? U1b : U0b;
            float2 r;
            r.x = ua.x*a0.x - ua.y*a0.y + ub.x*a1.x - ub.y*a1.y;
            r.y = ua.x*a0.y + ua.y*a0.x + ub.x*a1.y + ub.y*a1.x;
            st[cur ^ 1][i] = r;
            cur ^= 1;
            __syncthreads();
        }
        // fused CNOT ring
        float2 r = st[cur][psrc];
        st[cur ^ 1][i] = r;
        cur ^= 1;
        __syncthreads();
    }

    // column j of W: thread i<128 -> Wre[i][j], thread i>=128 -> Wim[i-128][j]
    const int m = i & 127;
    float2 a = st[cur][m];
    if (i < 128) W[(uint32_t)m*256u + (uint32_t)j]          = f2bf(a.x);
    else         W[32768u + (uint32_t)m*256u + (uint32_t)j] = f2bf(a.y);
}

// ---------------------------------------------------------------------------
// Kernel 2: out[m] = sum_j |sum_k W[j][k]*(sr[m][k] + i si[m][k])|^2
//
// Decomposition (round 4) + race fix (round 5):
//   - 512 blocks x 512 threads (8 waves). 2 blocks/CU (66 KB LDS, <=128 reg).
//   - Waves split J: wave w owns j = w*16..w*16+15; its B fragments
//     (16 x bf16x8 = 64 VGPRs) loaded once, stay in registers.
//   - A shared by all waves: 2 x 32 KB LDS double buffer staged via
//     global_load_lds (source-swizzled / read-deswizzled), counted
//     s_waitcnt vmcnt(4) -> DMA queue never drains in the loop.
//   - RACE FIX: raw s_barrier does NOT drain lgkmcnt; the red[] ds_write ->
//     barrier2 -> ds_read handoff needs an explicit
//     "s_waitcnt lgkmcnt(0)" BEFORE barrier2 (round-4 tripwire failure).
//     sched_barrier(0) after barrier1 pins Abuf ds_reads below the barrier.
// ---------------------------------------------------------------------------

#define STAGE(B) { \
    gload_lds16(&Abuf[B][(r0+0)*DIM], srcp0); srcp0 += 16*DIM; \
    gload_lds16(&Abuf[B][(r0+1)*DIM], srcp1); srcp1 += 16*DIM; \
    gload_lds16(&Abuf[B][(r0+2)*DIM], srcp2); srcp2 += 16*DIM; \
    gload_lds16(&Abuf[B][(r0+3)*DIM], srcp3); srcp3 += 16*DIM; }

#define BSTEP(S) { \
    f32x4 ra0 = *(const f32x4*)(arow + S*32 + o0); \
    f32x4 ra1 = *(const f32x4*)(arow + S*32 + o1); \
    f32x4 qa0 = *(const f32x4*)(irow + S*32 + o0); \
    f32x4 qa1 = *(const f32x4*)(irow + S*32 + o1); \
    union { f32x4 v; uint32_t u[4]; } ha_, hb_; \
    union { uint32_t u[4]; bf16x8 f; } pr_, pi_, pn_; \
    ha_.v = ra0; hb_.v = ra1; \
    pr_.u[0] = __builtin_amdgcn_perm(ha_.u[1], ha_.u[0], 0x07060302); \
    pr_.u[1] = __builtin_amdgcn_perm(ha_.u[3], ha_.u[2], 0x07060302); \
    pr_.u[2] = __builtin_amdgcn_perm(hb_.u[1], hb_.u[0], 0x07060302); \
    pr_.u[3] = __builtin_amdgcn_perm(hb_.u[3], hb_.u[2], 0x07060302); \
    ha_.v = qa0; hb_.v = qa1; \
    pi_.u[0] = __builtin_amdgcn_perm(ha_.u[1], ha_.u[0], 0x07060302); \
    pi_.u[1] = __builtin_amdgcn_perm(ha_.u[3], ha_.u[2], 0x07060302); \
    pi_.u[2] = __builtin_amdgcn_perm(hb_.u[1], hb_.u[0], 0x07060302); \
    pi_.u[3] = __builtin_amdgcn_perm(hb_.u[3], hb_.u[2], 0x07060302); \
    pn_.u[0] = pi_.u[0] ^ 0x80008000u; \
    pn_.u[1] = pi_.u[1] ^ 0x80008000u; \
    pn_.u[2] = pi_.u[2] ^ 0x80008000u; \
    pn_.u[3] = pi_.u[3] ^ 0x80008000u; \
    accR = __builtin_amdgcn_mfma_f32_16x16x32_bf16(pr_.f, bre_##S, accR, 0, 0, 0); \
    accR = __builtin_amdgcn_mfma_f32_16x16x32_bf16(pn_.f, bim_##S, accR, 0, 0, 0); \
    accI = __builtin_amdgcn_mfma_f32_16x16x32_bf16(pr_.f, bim_##S, accI, 0, 0, 0); \
    accI = __builtin_amdgcn_mfma_f32_16x16x32_bf16(pi_.f, bre_##S, accI, 0, 0, 0); \
}

__global__ __launch_bounds__(512, 4) void qform3_kernel(const float* __restrict__ sr,
                                                        const float* __restrict__ si,
                                                        const unsigned short* __restrict__ W,
                                                        float* __restrict__ out){
    __shared__ float Abuf[2][32*DIM];   // 2 x 32 KB A tile (16 sr rows + 16 si rows)
    __shared__ float red[128];          // 8 waves x 16 rows

    const int tid  = threadIdx.x;
    const int lane = tid & 63;
    const int w    = tid >> 6;        // 0..7  (= j block w*16..w*16+15)
    const int l15  = lane & 15;
    const int quad = lane >> 4;       // 0..3
    const int x7   = l15 & 7;
    const size_t m0 = (size_t)blockIdx.x * 256;   // 256 rows per block, 16 tiles

    // ---- staging sources: wave w stages tile-rows r0..r0+3
    // rows 0..15 = sr rows (m0+r), rows 16..31 = si rows (m0+r-16).
    // Source granule pre-swizzled: lane l supplies granule (l ^ (row&7)),
    // DMA writes it to LDS slot l -> read side XORs it back out.
    const int r0 = w * 4;
    const float* plane = (w < 4) ? sr : si;
    const float* srcp0 = plane + (m0 + ((r0+0)&15))*DIM + ((lane ^ ((r0+0)&7)) << 2);
    const float* srcp1 = plane + (m0 + ((r0+1)&15))*DIM + ((lane ^ ((r0+1)&7)) << 2);
    const float* srcp2 = plane + (m0 + ((r0+2)&15))*DIM + ((lane ^ ((r0+2)&7)) << 2);
    const float* srcp3 = plane + (m0 + ((r0+3)&15))*DIM + ((lane ^ ((r0+3)&7)) << 2);

    // prologue: stage tile 0 into buffer 0 (starts the HBM stream early)
    STAGE(0)

    // ---- B fragments in registers: lane (l15,quad) of wave w holds, per
    // kstep S, W[w*16+l15][S*32 + quad*8 .. +7] for both planes. 64 VGPRs.
    const unsigned short* wre = W + ((uint32_t)(w*16 + l15))*256u + (uint32_t)(quad*8);
    const unsigned short* wim = wre + 32768u;
    const bf16x8 bre_0 = *(const bf16x8*)(wre + 0*32);
    const bf16x8 bre_1 = *(const bf16x8*)(wre + 1*32);
    const bf16x8 bre_2 = *(const bf16x8*)(wre + 2*32);
    const bf16x8 bre_3 = *(const bf16x8*)(wre + 3*32);
    const bf16x8 bre_4 = *(const bf16x8*)(wre + 4*32);
    const bf16x8 bre_5 = *(const bf16x8*)(wre + 5*32);
    const bf16x8 bre_6 = *(const bf16x8*)(wre + 6*32);
    const bf16x8 bre_7 = *(const bf16x8*)(wre + 7*32);
    const bf16x8 bim_0 = *(const bf16x8*)(wim + 0*32);
    const bf16x8 bim_1 = *(const bf16x8*)(wim + 1*32);
    const bf16x8 bim_2 = *(const bf16x8*)(wim + 2*32);
    const bf16x8 bim_3 = *(const bf16x8*)(wim + 3*32);
    const bf16x8 bim_4 = *(const bf16x8*)(wim + 4*32);
    const bf16x8 bim_5 = *(const bf16x8*)(wim + 5*32);
    const bf16x8 bim_6 = *(const bf16x8*)(wim + 6*32);
    const bf16x8 bim_7 = *(const bf16x8*)(wim + 7*32);

    // read-side swizzle offsets (float units): granule (quad*2+c) ^ x7
    const int o0 = (((quad << 1)    ) ^ x7) << 2;
    const int o1 = (((quad << 1) | 1) ^ x7) << 2;

    int buf = 0;
    #pragma unroll 1
    for (int t = 0; t < 16; ++t){
        if (t < 15){
            STAGE(buf ^ 1)
            // wait for CURRENT tile's DMA (FIFO: leaves the just-issued
            // next-tile loads in flight -> queue never drains)
            asm volatile("s_waitcnt vmcnt(4)" ::: "memory");
        } else {
            asm volatile("s_waitcnt vmcnt(0)" ::: "memory");
        }
        __builtin_amdgcn_s_barrier();
        __builtin_amdgcn_sched_barrier(0);   // pin Abuf reads below barrier

        const float* arow = &Abuf[buf][l15 * DIM];          // sr row
        const float* irow = &Abuf[buf][(16 + l15) * DIM];   // si row

        f32x4 accR = {0.0f, 0.0f, 0.0f, 0.0f};
        f32x4 accI = {0.0f, 0.0f, 0.0f, 0.0f};
        BSTEP(0) BSTEP(1) BSTEP(2) BSTEP(3)
        BSTEP(4) BSTEP(5) BSTEP(6) BSTEP(7)

        // ---- reduce over this wave's 16 j's (C cols = l15), then stash
        // per-row partial. C/D layout: row = quad*4 + r, col = l15.
        #pragma unroll
        for (int r = 0; r < 4; ++r){
            const float vr = accR[r], vi = accI[r];
            float tt = vr*vr + vi*vi;
            tt += __shfl_xor(tt, 1);
            tt += __shfl_xor(tt, 2);
            tt += __shfl_xor(tt, 4);
            tt += __shfl_xor(tt, 8);
            if (l15 == 0) red[w*16 + quad*4 + r] = tt;
        }
        // RACE FIX: drain the red[] ds_writes before the raw barrier —
        // s_barrier alone does NOT wait lgkmcnt, reader waves saw stale LDS.
        asm volatile("s_waitcnt lgkmcnt(0)" ::: "memory");
        __builtin_amdgcn_s_barrier();        // also protects Abuf[buf] reuse
        __builtin_amdgcn_sched_barrier(0);

        if (tid < 16){
            float o = 0.0f;
            #pragma unroll
            for (int ww = 0; ww < 8; ++ww) o += red[ww*16 + tid];
            out[m0 + t*16 + tid] = o;
        }
        buf ^= 1;
    }
}

extern "C" void kernel_launch(void* const* d_in, const int* in_sizes, int n_in,
                              void* d_out, int out_size, void* d_ws, size_t ws_size,
                              hipStream_t stream){
    const float* params = (const float*)d_in[0];
    const float* sr     = (const float*)d_in[1];
    const float* si     = (const float*)d_in[2];
    unsigned short* Wimg = (unsigned short*)d_ws;   // 128 KB image
    float* out          = (float*)d_out;

    build_w_kernel<<<dim3(DIM), dim3(256), 0, stream>>>(params, Wimg);
    qform3_kernel<<<dim3(512), dim3(512), 0, stream>>>(sr, si, Wimg, out);
}